// Round 1
// baseline (764.454 us; speedup 1.0000x reference)
//
#include <hip/hip_runtime.h>
#include <hip/hip_bf16.h>

#define D      256
#define NH     8
#define HD     32
#define TOPK   128
#define CAP    512
#define BN     64
#define ZTHRESH 3.0f

typedef __bf16 bf16x8 __attribute__((ext_vector_type(8)));
typedef float  f32x4  __attribute__((ext_vector_type(4)));

static __device__ __forceinline__ unsigned short bf16_trunc(float f) {
    return (unsigned short)(__builtin_bit_cast(unsigned int, f) >> 16);
}

// ---------------- prep: query fp32 -> bf16 (trunc) packed in MFMA A-fragment order ------------
// Apack[((mt*8 + ks)*64 + lane)*8 + j] = A[mt*16 + (lane&15)][ks*32 + (lane>>4)*8 + j]
// so coarse's af load is one coalesced dwordx4 per lane (1 KiB per wave).
__global__ void prep_kernel(const float* __restrict__ Q, unsigned short* __restrict__ Apack,
                            float* __restrict__ T, unsigned int* __restrict__ cnt) {
    int b = blockIdx.x;
    int lane = threadIdx.x;            // 0..63, handles cols 4*lane..4*lane+3
    float4 v = ((const float4*)(Q + b * D))[lane];
    ushort4 h;
    h.x = bf16_trunc(v.x); h.y = bf16_trunc(v.y); h.z = bf16_trunc(v.z); h.w = bf16_trunc(v.w);
    int mt = b >> 4, r = b & 15;
    int ks = lane >> 3;                // k-block of 32
    int q  = (lane >> 1) & 3;          // quad within fragment (k bits 3..4)
    int j4 = (lane & 1) * 4;           // half within the 8-element fragment
    size_t off = (((size_t)(mt * 8 + ks)) * 64 + (q * 16 + r)) * 8 + j4;
    *(ushort4*)(Apack + off) = h;
    float ss = v.x*v.x + v.y*v.y + v.z*v.z + v.w*v.w;
    for (int off2 = 32; off2; off2 >>= 1) ss += __shfl_down(ss, off2);
    if (lane == 0) { T[b] = ZTHRESH * sqrtf(ss); cnt[b] = 0u; }
}

// ---------------- fused weights: Wq_eff = Wq@W_cq, Wk_eff = Wk@W_cd, Wv_eff = Wv@W_cd + biases -
__global__ void weights_kernel(const float* __restrict__ in_w, const float* __restrict__ in_b,
                               const float* __restrict__ W_cq, const float* __restrict__ b_cq,
                               const float* __restrict__ W_cd, const float* __restrict__ b_cd,
                               float* __restrict__ Wq_eff, float* __restrict__ Wk_eff,
                               float* __restrict__ Wv_eff,
                               float* __restrict__ qh_bias, float* __restrict__ vh_bias) {
    int which = blockIdx.x >> 8;       // 0=q 1=k 2=v
    int i = blockIdx.x & 255;          // output row
    int t = threadIdx.x;               // output col
    __shared__ float wrow[D];
    __shared__ float red[256];
    const float* Wsub = in_w + (size_t)which * D * D + (size_t)i * D;
    wrow[t] = Wsub[t];
    __syncthreads();
    const float* Wc = (which == 0) ? W_cq : W_cd;
    // 4 independent accumulators: breaks the serial FMA chain (rerank tolerance is 2%)
    float a0 = 0.f, a1 = 0.f, a2 = 0.f, a3 = 0.f;
    for (int d = 0; d < D; d += 4) {
        a0 += wrow[d + 0] * Wc[(d + 0) * D + t];
        a1 += wrow[d + 1] * Wc[(d + 1) * D + t];
        a2 += wrow[d + 2] * Wc[(d + 2) * D + t];
        a3 += wrow[d + 3] * Wc[(d + 3) * D + t];
    }
    float acc = (a0 + a1) + (a2 + a3);
    float* dst = (which == 0) ? Wq_eff : ((which == 1) ? Wk_eff : Wv_eff);
    dst[(size_t)i * D + t] = acc;
    const float* bc = (which == 0) ? b_cq : b_cd;
    red[t] = wrow[t] * bc[t];
    __syncthreads();
    for (int s = 128; s; s >>= 1) { if (t < s) red[t] += red[t + s]; __syncthreads(); }
    if (t == 0) {
        float bias = red[0] + in_b[which * D + i];
        if (which == 0) qh_bias[i] = bias;
        else if (which == 2) vh_bias[i] = bias;   // k-bias is softmax-invariant, dropped
    }
}

// ---------------- coarse: bf16 MFMA scores + threshold filter append ---------------------------
// Persistent grid-stride (768 blocks = 3/CU) + register double-buffered staging (T14):
// tile t+1's 16 global_load_dwordx4 per thread are issued BEFORE the MFMA phase of tile t,
// so HBM stays busy during compute and the MFMA pipe stays busy during staging.
// __launch_bounds__(256,3): VGPR cap 170 — live set ~150 (acc 32 + stage 64 + frags + addr).
__global__ __launch_bounds__(256, 3)
void coarse_kernel(const float* __restrict__ X, const unsigned short* __restrict__ Apack,
                   const float* __restrict__ T, unsigned int* __restrict__ cnt,
                   int* __restrict__ cand, int N, int B, int ntiles) {
    __shared__ unsigned short Bs[BN * D];   // 32 KiB, 16B-granule XOR swizzle
    __shared__ float Ts[512];               // thresholds, loaded once per persistent block
    int t = threadIdx.x;
    int w = t >> 6, lane = t & 63;
    int l15 = lane & 15, q4 = lane >> 4;

    Ts[t] = T[t];
    Ts[t + 256] = T[t + 256];

    long tile = blockIdx.x;
    if (tile >= ntiles) return;

    const float4* X4 = (const float4*)X;
    float4 v[16];     // staged tile: thread holds rows w,w+4,..,w+60 at float4-col `lane`

    // prologue: issue tile-0 loads (16 independent dwordx4 per thread)
    {
        long nbase = tile * BN;
        #pragma unroll
        for (int it = 0; it < 16; ++it) {
            long gi = nbase + it * 4 + w;
            float4 z = make_float4(0.f, 0.f, 0.f, 0.f);
            v[it] = (gi < N) ? X4[gi * 64 + lane] : z;
        }
    }

    for (;;) {
        // ---- drain loads, pack fp32->bf16, write LDS ----
        #pragma unroll
        for (int it = 0; it < 16; ++it) {
            int n = it * 4 + w;
            uint2 pk;
            pk.x = (__builtin_bit_cast(unsigned int, v[it].x) >> 16) |
                   (__builtin_bit_cast(unsigned int, v[it].y) & 0xFFFF0000u);
            pk.y = (__builtin_bit_cast(unsigned int, v[it].z) >> 16) |
                   (__builtin_bit_cast(unsigned int, v[it].w) & 0xFFFF0000u);
            int gran = (lane >> 1) ^ (n & 7);
            ((uint2*)Bs)[n * 64 + gran * 2 + (lane & 1)] = pk;
        }
        __syncthreads();

        long nbase = tile * BN;
        long next = tile + gridDim.x;
        bool have = (next < (long)ntiles);
        if (have) {                      // issue next tile's loads BEFORE compute (T14)
            long nb2 = next * BN;
            #pragma unroll
            for (int it = 0; it < 16; ++it) {
                long gi = nb2 + it * 4 + w;
                float4 z = make_float4(0.f, 0.f, 0.f, 0.f);
                v[it] = (gi < N) ? X4[gi * 64 + lane] : z;
            }
        }

        // ---- MFMA + filter epilogue (reads LDS only; next-tile loads in flight) ----
        for (int p = 0; p < 4; ++p) {            // m-pass: 128 rows, wave w owns 32 of them
            f32x4 acc[2][4];
            #pragma unroll
            for (int mt = 0; mt < 2; ++mt)
                #pragma unroll
                for (int nt = 0; nt < 4; ++nt) acc[mt][nt] = (f32x4){0.f, 0.f, 0.f, 0.f};

            #pragma unroll
            for (int ks = 0; ks < 8; ++ks) {
                bf16x8 af[2], bf[4];
                #pragma unroll
                for (int mtl = 0; mtl < 2; ++mtl) {
                    int mtg = p * 8 + w * 2 + mtl;
                    af[mtl] = *(const bf16x8*)(const void*)(Apack + (((size_t)(mtg * 8 + ks)) * 64 + lane) * 8);
                }
                #pragma unroll
                for (int nt = 0; nt < 4; ++nt) {
                    int n = nt * 16 + l15;
                    int gran = (ks * 4 + q4) ^ (n & 7);
                    bf[nt] = *(const bf16x8*)(const void*)(Bs + n * D + gran * 8);
                }
                #pragma unroll
                for (int mtl = 0; mtl < 2; ++mtl)
                    #pragma unroll
                    for (int nt = 0; nt < 4; ++nt)
                        acc[mtl][nt] = __builtin_amdgcn_mfma_f32_16x16x32_bf16(
                            af[mtl], bf[nt], acc[mtl][nt], 0, 0, 0);
            }
            // filter epilogue: D[row=m][col=n], row=(lane>>4)*4+r, col=lane&15 (verified R4)
            #pragma unroll
            for (int mtl = 0; mtl < 2; ++mtl) {
                int mbase = p * 128 + w * 32 + mtl * 16 + q4 * 4;
                float4 Tv = *(const float4*)(Ts + mbase);
                float Ta[4] = {Tv.x, Tv.y, Tv.z, Tv.w};
                #pragma unroll
                for (int nt = 0; nt < 4; ++nt) {
                    long n_global = nbase + nt * 16 + l15;
                    #pragma unroll
                    for (int r = 0; r < 4; ++r) {
                        float s = acc[mtl][nt][r];
                        if (n_global < N && s >= Ta[r]) {
                            int m = mbase + r;
                            unsigned int pos = atomicAdd(&cnt[m], 1u);
                            if (pos < CAP) cand[(size_t)m * CAP + pos] = (int)n_global;
                        }
                    }
                }
            }
        }

        __syncthreads();                 // all waves done reading Bs before overwrite
        if (!have) break;
        tile = next;
    }
}

// ---------------- fine: fp32 sequential-FMA re-score (sgemm-bit-exact) + bitonic top-128 ------
__global__ __launch_bounds__(512)
void fine_kernel(const float* __restrict__ Q, const float* __restrict__ X,
                 const unsigned int* __restrict__ cnt, const int* __restrict__ cand,
                 int* __restrict__ sel, float* __restrict__ out_idx,
                 float* __restrict__ out_sc) {
    int b = blockIdx.x, t = threadIdx.x;    // 512 threads: one candidate per thread
    __shared__ float qs[D];
    __shared__ float sc[CAP];
    __shared__ int   id[CAP];
    if (t < D) qs[t] = Q[(size_t)b * D + t];
    __syncthreads();
    int m = (int)cnt[b]; if (m > CAP) m = CAP;

    // strict sequential fp32 FMA, ascending k — bit-exact vs numpy's sgemm microkernel
    {
        int j = t;
        float s; int idx;
        if (j < m) {
            idx = cand[(size_t)b * CAP + j];
            const float4* xr = (const float4*)(X + (long)idx * D);
            s = 0.f;
            for (int c = 0; c < 64; ++c) {
                float4 xv = xr[c];
                s = fmaf(qs[c * 4 + 0], xv.x, s);
                s = fmaf(qs[c * 4 + 1], xv.y, s);
                s = fmaf(qs[c * 4 + 2], xv.z, s);
                s = fmaf(qs[c * 4 + 3], xv.w, s);
            }
        } else { idx = 0x7FFFFFFF; s = -3.4e38f; }
        sc[j] = s; id[j] = idx;
    }
    __syncthreads();
    // bitonic: descending score, ascending idx on ties
    for (int k = 2; k <= CAP; k <<= 1)
        for (int j = k >> 1; j > 0; j >>= 1) {
            int i = t;
            int ixj = i ^ j;
            if (ixj > i) {
                float s1 = sc[i], s2 = sc[ixj];
                int i1 = id[i], i2 = id[ixj];
                bool before = (s1 > s2) || (s1 == s2 && i1 < i2);
                bool up = ((i & k) == 0);
                if (up != before) { sc[i] = s2; sc[ixj] = s1; id[i] = i2; id[ixj] = i1; }
            }
            __syncthreads();
        }
    if (t < TOPK) {
        int idx = id[t];
        out_idx[b * TOPK + t] = (float)idx;
        out_sc [b * TOPK + t] = sc[t];
        sel[b * TOPK + t] = idx;
    }
}

// ---------------- rerank: cross-attention contracted through head bottleneck (fp32) -----------
__global__ __launch_bounds__(256)
void rerank_kernel(const float* __restrict__ Q, const float* __restrict__ X,
                   const int* __restrict__ sel,
                   const float* __restrict__ Wq_eff, const float* __restrict__ Wk_eff,
                   const float* __restrict__ Wv_eff,
                   const float* __restrict__ qh_bias, const float* __restrict__ vh_bias,
                   const float* __restrict__ out_w, const float* __restrict__ out_b,
                   const float* __restrict__ W_s1, const float* __restrict__ b_s1,
                   const float* __restrict__ W_s2, const float* __restrict__ b_s2,
                   float* __restrict__ out_rr) {
    int b = blockIdx.x, t = threadIdx.x;
    __shared__ float qvec[D];
    __shared__ float qh[D];
    __shared__ float u[NH][D];
    __shared__ float att[NH][TOPK];
    __shared__ float wbar[NH][D];
    __shared__ float ctx[D];
    __shared__ float cross[D];
    __shared__ float h1[TOPK];
    __shared__ float red[256];

    qvec[t] = Q[(size_t)b * D + t];
    for (int i = t; i < NH * D; i += 256) (&wbar[0][0])[i] = 0.f;
    __syncthreads();

    {   // qh = query @ Wq_eff.T + qh_bias
        float acc = qh_bias[t];
        const float* wr = Wq_eff + (size_t)t * D;
        for (int d = 0; d < D; d += 4) {
            float4 wv = *(const float4*)(wr + d);
            acc += wv.x*qvec[d] + wv.y*qvec[d+1] + wv.z*qvec[d+2] + wv.w*qvec[d+3];
        }
        qh[t] = acc;
    }
    __syncthreads();
    {   // u[h][d] = sum_i qh[h*32+i] * Wk_eff[h*32+i][d], scaled by 1/sqrt(HD)
        const float scale = 0.17677669529663687f;
        for (int h = 0; h < NH; ++h) {
            float acc = 0.f;
            #pragma unroll 8
            for (int i = 0; i < HD; ++i)
                acc += qh[h * HD + i] * Wk_eff[(size_t)(h * HD + i) * D + t];
            u[h][t] = acc * scale;
        }
    }
    __syncthreads();
    {   // logits[h][k] = u[h] . cand_k
        int k = t & 127, hg = t >> 7;
        const float* xr = X + (long)sel[b * TOPK + k] * D;
        float acc[4] = {0.f, 0.f, 0.f, 0.f};
        for (int d = 0; d < D; d += 4) {
            float4 xv = *(const float4*)(xr + d);
            #pragma unroll
            for (int hh = 0; hh < 4; ++hh) {
                int h = hg + hh * 2;
                acc[hh] += u[h][d]*xv.x + u[h][d+1]*xv.y + u[h][d+2]*xv.z + u[h][d+3]*xv.w;
            }
        }
        #pragma unroll
        for (int hh = 0; hh < 4; ++hh) att[hg + hh * 2][k] = acc[hh];
    }
    __syncthreads();
    {   // softmax over k per head
        int w = t >> 6, lane = t & 63;
        for (int h = w; h < NH; h += 4) {
            float v0 = att[h][lane], v1 = att[h][lane + 64];
            float mx = fmaxf(v0, v1);
            for (int off = 32; off; off >>= 1) mx = fmaxf(mx, __shfl_down(mx, off));
            mx = __shfl(mx, 0);
            float e0 = expf(v0 - mx), e1 = expf(v1 - mx);
            float sm = e0 + e1;
            for (int off = 32; off; off >>= 1) sm += __shfl_down(sm, off);
            sm = __shfl(sm, 0);
            float inv = 1.f / sm;
            att[h][lane] = e0 * inv; att[h][lane + 64] = e1 * inv;
        }
    }
    __syncthreads();
    {   // wbar[h] = sum_k attn[h][k] * cand_k
        int w = t >> 6, lane = t & 63;
        float4 acc[NH];
        #pragma unroll
        for (int h = 0; h < NH; ++h) acc[h] = make_float4(0.f, 0.f, 0.f, 0.f);
        for (int kk = 0; kk < 32; ++kk) {
            int k = w * 32 + kk;
            const float* xr = X + (long)sel[b * TOPK + k] * D;
            float4 xv = ((const float4*)xr)[lane];
            #pragma unroll
            for (int h = 0; h < NH; ++h) {
                float a = att[h][k];
                acc[h].x += a * xv.x; acc[h].y += a * xv.y;
                acc[h].z += a * xv.z; acc[h].w += a * xv.w;
            }
        }
        #pragma unroll
        for (int h = 0; h < NH; ++h) {
            atomicAdd(&wbar[h][lane * 4 + 0], acc[h].x);
            atomicAdd(&wbar[h][lane * 4 + 1], acc[h].y);
            atomicAdd(&wbar[h][lane * 4 + 2], acc[h].z);
            atomicAdd(&wbar[h][lane * 4 + 3], acc[h].w);
        }
    }
    __syncthreads();
    {   // ctx[i] = Wv_eff[i] . wbar[i>>5] + vh_bias[i]
        int h = t >> 5;
        float acc = vh_bias[t];
        const float* wr = Wv_eff + (size_t)t * D;
        const float* wb = wbar[h];
        for (int d = 0; d < D; d += 4) {
            float4 wv = *(const float4*)(wr + d);
            acc += wv.x*wb[d] + wv.y*wb[d+1] + wv.z*wb[d+2] + wv.w*wb[d+3];
        }
        ctx[t] = acc;
    }
    __syncthreads();
    {   // cross_out
        float acc = out_b[t];
        const float* wr = out_w + (size_t)t * D;
        for (int d = 0; d < D; d += 4) {
            float4 wv = *(const float4*)(wr + d);
            acc += wv.x*ctx[d] + wv.y*ctx[d+1] + wv.z*ctx[d+2] + wv.w*ctx[d+3];
        }
        cross[t] = acc;
    }
    __syncthreads();
    if (t < TOPK) {   // h1 = relu(cross @ W_s1.T + b_s1)
        float acc = b_s1[t];
        const float* wr = W_s1 + (size_t)t * D;
        for (int d = 0; d < D; d += 4) {
            float4 wv = *(const float4*)(wr + d);
            acc += wv.x*cross[d] + wv.y*cross[d+1] + wv.z*cross[d+2] + wv.w*cross[d+3];
        }
        h1[t] = fmaxf(acc, 0.f);
    }
    __syncthreads();
    red[t] = (t < TOPK) ? h1[t] * W_s2[t] : 0.f;
    __syncthreads();
    for (int s = 128; s; s >>= 1) { if (t < s) red[t] += red[t + s]; __syncthreads(); }
    if (t == 0) out_rr[b] = red[0] + b_s2[0];
}

// ---------------- launch ----------------------------------------------------------------------
extern "C" void kernel_launch(void* const* d_in, const int* in_sizes, int n_in,
                              void* d_out, int out_size, void* d_ws, size_t ws_size,
                              hipStream_t stream) {
    const float* Q    = (const float*)d_in[0];
    const float* X    = (const float*)d_in[1];
    const float* W_cq = (const float*)d_in[2];
    const float* b_cq = (const float*)d_in[3];
    const float* W_cd = (const float*)d_in[4];
    const float* b_cd = (const float*)d_in[5];
    const float* in_w = (const float*)d_in[6];
    const float* in_b = (const float*)d_in[7];
    const float* ow   = (const float*)d_in[8];
    const float* ob   = (const float*)d_in[9];
    const float* Ws1  = (const float*)d_in[10];
    const float* bs1  = (const float*)d_in[11];
    const float* Ws2  = (const float*)d_in[12];
    const float* bs2  = (const float*)d_in[13];
    int B = in_sizes[0] / D;     // 512
    int N = in_sizes[1] / D;     // 200000

    char* ws = (char*)d_ws;
    unsigned short* Apack = (unsigned short*)ws;                      // B*D*2 (fragment-packed)
    float*          T     = (float*)(ws + (size_t)B * D * 2);         // B*4
    unsigned int*   cnt   = (unsigned int*)(ws + (size_t)B * D * 2 + B * 4);
    int*            cand  = (int*)(ws + (size_t)B * D * 2 + B * 8);   // B*CAP*4
    int*            sel   = (int*)((char*)cand + (size_t)B * CAP * 4);// B*TOPK*4
    float*          Wq_eff = (float*)((char*)sel + (size_t)B * TOPK * 4);
    float*          Wk_eff = Wq_eff + D * D;
    float*          Wv_eff = Wk_eff + D * D;
    float*          qh_b   = Wv_eff + D * D;
    float*          vh_b   = qh_b + D;

    float* ofl     = (float*)d_out;                 // fp32 output buffer
    float* out_idx = ofl;                           // [B*TOPK] indices as floats
    float* out_sc  = ofl + (size_t)B * TOPK;        // [B*TOPK] scores
    float* out_rr  = ofl + (size_t)2 * B * TOPK;    // [B] rerank scores

    prep_kernel<<<B, 64, 0, stream>>>(Q, Apack, T, cnt);
    weights_kernel<<<3 * D, 256, 0, stream>>>(in_w, in_b, W_cq, b_cq, W_cd, b_cd,
                                              Wq_eff, Wk_eff, Wv_eff, qh_b, vh_b);
    int nblk = (N + BN - 1) / BN;
    int grid = nblk < 768 ? nblk : 768;   // persistent: 3 blocks/CU x 256 CUs
    coarse_kernel<<<grid, 256, 0, stream>>>(X, Apack, T, cnt, cand, N, B, nblk);
    fine_kernel<<<B, 512, 0, stream>>>(Q, X, cnt, cand, sel, out_idx, out_sc);
    rerank_kernel<<<B, 256, 0, stream>>>(Q, X, sel, Wq_eff, Wk_eff, Wv_eff, qh_b, vh_b,
                                         ow, ob, Ws1, bs1, Ws2, bs2, out_rr);
}

// Round 2
// 616.648 us; speedup vs baseline: 1.2397x; 1.2397x over previous
//
#include <hip/hip_runtime.h>
#include <hip/hip_bf16.h>

#define D      256
#define NH     8
#define HD     32
#define TOPK   128
#define CAP    512
#define BN     32
#define ZTHRESH 3.0f

typedef __bf16 bf16x8 __attribute__((ext_vector_type(8)));
typedef float  f32x4  __attribute__((ext_vector_type(4)));

static __device__ __forceinline__ unsigned short bf16_trunc(float f) {
    return (unsigned short)(__builtin_bit_cast(unsigned int, f) >> 16);
}

// ---------------- prep: query fp32 -> bf16 (trunc) packed in MFMA A-fragment order ------------
// Apack[((mt*8 + ks)*64 + lane)*8 + j] = A[mt*16 + (lane&15)][ks*32 + (lane>>4)*8 + j]
// so coarse's af load is one coalesced dwordx4 per lane (1 KiB per wave).
__global__ void prep_kernel(const float* __restrict__ Q, unsigned short* __restrict__ Apack,
                            float* __restrict__ T, unsigned int* __restrict__ cnt) {
    int b = blockIdx.x;
    int lane = threadIdx.x;            // 0..63, handles cols 4*lane..4*lane+3
    float4 v = ((const float4*)(Q + b * D))[lane];
    ushort4 h;
    h.x = bf16_trunc(v.x); h.y = bf16_trunc(v.y); h.z = bf16_trunc(v.z); h.w = bf16_trunc(v.w);
    int mt = b >> 4, r = b & 15;
    int ks = lane >> 3;                // k-block of 32
    int q  = (lane >> 1) & 3;          // quad within fragment (k bits 3..4)
    int j4 = (lane & 1) * 4;           // half within the 8-element fragment
    size_t off = (((size_t)(mt * 8 + ks)) * 64 + (q * 16 + r)) * 8 + j4;
    *(ushort4*)(Apack + off) = h;
    float ss = v.x*v.x + v.y*v.y + v.z*v.z + v.w*v.w;
    for (int off2 = 32; off2; off2 >>= 1) ss += __shfl_down(ss, off2);
    if (lane == 0) { T[b] = ZTHRESH * sqrtf(ss); cnt[b] = 0u; }
}

// ---------------- fused weights: Wq_eff = Wq@W_cq, Wk_eff = Wk@W_cd, Wv_eff = Wv@W_cd + biases -
__global__ void weights_kernel(const float* __restrict__ in_w, const float* __restrict__ in_b,
                               const float* __restrict__ W_cq, const float* __restrict__ b_cq,
                               const float* __restrict__ W_cd, const float* __restrict__ b_cd,
                               float* __restrict__ Wq_eff, float* __restrict__ Wk_eff,
                               float* __restrict__ Wv_eff,
                               float* __restrict__ qh_bias, float* __restrict__ vh_bias) {
    int which = blockIdx.x >> 8;       // 0=q 1=k 2=v
    int i = blockIdx.x & 255;          // output row
    int t = threadIdx.x;               // output col
    __shared__ float wrow[D];
    __shared__ float red[256];
    const float* Wsub = in_w + (size_t)which * D * D + (size_t)i * D;
    wrow[t] = Wsub[t];
    __syncthreads();
    const float* Wc = (which == 0) ? W_cq : W_cd;
    // 4 independent accumulators: breaks the serial FMA chain (rerank tolerance is 2%)
    float a0 = 0.f, a1 = 0.f, a2 = 0.f, a3 = 0.f;
    for (int d = 0; d < D; d += 4) {
        a0 += wrow[d + 0] * Wc[(d + 0) * D + t];
        a1 += wrow[d + 1] * Wc[(d + 1) * D + t];
        a2 += wrow[d + 2] * Wc[(d + 2) * D + t];
        a3 += wrow[d + 3] * Wc[(d + 3) * D + t];
    }
    float acc = (a0 + a1) + (a2 + a3);
    float* dst = (which == 0) ? Wq_eff : ((which == 1) ? Wk_eff : Wv_eff);
    dst[(size_t)i * D + t] = acc;
    const float* bc = (which == 0) ? b_cq : b_cd;
    red[t] = wrow[t] * bc[t];
    __syncthreads();
    for (int s = 128; s; s >>= 1) { if (t < s) red[t] += red[t + s]; __syncthreads(); }
    if (t == 0) {
        float bias = red[0] + in_b[which * D + i];
        if (which == 0) qh_bias[i] = bias;
        else if (which == 2) vh_bias[i] = bias;   // k-bias is softmax-invariant, dropped
    }
}

// ---------------- coarse: bf16 MFMA scores + threshold filter append ---------------------------
// BN=32 tile (16 KiB LDS) + 8 NAMED-register hoisted stage loads (deep issue, no scratch)
// + 5 blocks/CU TLP for latency hiding. Stage loads fully drain before compute -> the wave's
// in-compute Apack loads never vmcnt-drain another wave's stage (vmcnt is per-wave).
__global__ __launch_bounds__(256, 5)
void coarse_kernel(const float* __restrict__ X, const unsigned short* __restrict__ Apack,
                   const float* __restrict__ T, unsigned int* __restrict__ cnt,
                   int* __restrict__ cand, int N, int B) {
    __shared__ unsigned short Bs[BN * D];   // 16 KiB, 16B-granule XOR swizzle
    __shared__ float Ts[512];               // thresholds staged once per block
    int t = threadIdx.x;
    int w = t >> 6, lane = t & 63;
    int l15 = lane & 15, q4 = lane >> 4;
    long nbase = (long)blockIdx.x * BN;

    Ts[t] = T[t];
    Ts[t + 256] = T[t + 256];

    const float4* X4 = (const float4*)X;

    // ---- stage: 8 hoisted independent loads (rows i*4+w, float4-col = lane), then pack ----
    // Named variables (not an array) so SROA keeps them in VGPRs; loads issue back-to-back
    // and stay 8-deep in flight per wave before the first pack's wait.
#define LOADROW(i) long r##i = nbase + (i)*4 + w; if (r##i >= N) r##i = N - 1; \
                   float4 v##i = X4[r##i * 64 + lane];
    LOADROW(0) LOADROW(1) LOADROW(2) LOADROW(3)
    LOADROW(4) LOADROW(5) LOADROW(6) LOADROW(7)
#undef LOADROW
#define PACKROW(i) { int n = (i)*4 + w; uint2 pk; \
        pk.x = (__builtin_bit_cast(unsigned int, v##i.x) >> 16) | \
               (__builtin_bit_cast(unsigned int, v##i.y) & 0xFFFF0000u); \
        pk.y = (__builtin_bit_cast(unsigned int, v##i.z) >> 16) | \
               (__builtin_bit_cast(unsigned int, v##i.w) & 0xFFFF0000u); \
        int gran = (lane >> 1) ^ (n & 7); \
        ((uint2*)Bs)[n * 64 + gran * 2 + (lane & 1)] = pk; }
    PACKROW(0) PACKROW(1) PACKROW(2) PACKROW(3)
    PACKROW(4) PACKROW(5) PACKROW(6) PACKROW(7)
#undef PACKROW
    __syncthreads();

    // ---- MFMA + filter epilogue ----
    for (int p = 0; p < 4; ++p) {            // m-pass: 128 rows, wave w owns 32 of them
        f32x4 acc[2][2];
        #pragma unroll
        for (int mt = 0; mt < 2; ++mt)
            #pragma unroll
            for (int nt = 0; nt < 2; ++nt) acc[mt][nt] = (f32x4){0.f, 0.f, 0.f, 0.f};

        #pragma unroll
        for (int ks = 0; ks < 8; ++ks) {
            bf16x8 af[2], bf[2];
            #pragma unroll
            for (int mtl = 0; mtl < 2; ++mtl) {
                int mtg = p * 8 + w * 2 + mtl;
                af[mtl] = *(const bf16x8*)(const void*)(Apack + (((size_t)(mtg * 8 + ks)) * 64 + lane) * 8);
            }
            #pragma unroll
            for (int nt = 0; nt < 2; ++nt) {
                int n = nt * 16 + l15;
                int gran = (ks * 4 + q4) ^ (n & 7);
                bf[nt] = *(const bf16x8*)(const void*)(Bs + n * D + gran * 8);
            }
            #pragma unroll
            for (int mtl = 0; mtl < 2; ++mtl)
                #pragma unroll
                for (int nt = 0; nt < 2; ++nt)
                    acc[mtl][nt] = __builtin_amdgcn_mfma_f32_16x16x32_bf16(
                        af[mtl], bf[nt], acc[mtl][nt], 0, 0, 0);
        }
        // filter epilogue: D[row=m][col=n], row=(lane>>4)*4+r, col=lane&15 (verified R4)
        #pragma unroll
        for (int mtl = 0; mtl < 2; ++mtl) {
            int mbase = p * 128 + w * 32 + mtl * 16 + q4 * 4;
            float4 Tv = *(const float4*)(Ts + mbase);
            float Ta[4] = {Tv.x, Tv.y, Tv.z, Tv.w};
            #pragma unroll
            for (int nt = 0; nt < 2; ++nt) {
                long n_global = nbase + nt * 16 + l15;
                #pragma unroll
                for (int r = 0; r < 4; ++r) {
                    float s = acc[mtl][nt][r];
                    if (n_global < N && s >= Ta[r]) {
                        int m = mbase + r;
                        unsigned int pos = atomicAdd(&cnt[m], 1u);
                        if (pos < CAP) cand[(size_t)m * CAP + pos] = (int)n_global;
                    }
                }
            }
        }
    }
}

// ---------------- fine: fp32 sequential-FMA re-score (sgemm-bit-exact) + bitonic top-128 ------
__global__ __launch_bounds__(512)
void fine_kernel(const float* __restrict__ Q, const float* __restrict__ X,
                 const unsigned int* __restrict__ cnt, const int* __restrict__ cand,
                 int* __restrict__ sel, float* __restrict__ out_idx,
                 float* __restrict__ out_sc) {
    int b = blockIdx.x, t = threadIdx.x;    // 512 threads: one candidate per thread
    __shared__ float qs[D];
    __shared__ float sc[CAP];
    __shared__ int   id[CAP];
    if (t < D) qs[t] = Q[(size_t)b * D + t];
    __syncthreads();
    int m = (int)cnt[b]; if (m > CAP) m = CAP;

    // strict sequential fp32 FMA, ascending k — bit-exact vs numpy's sgemm microkernel
    {
        int j = t;
        float s; int idx;
        if (j < m) {
            idx = cand[(size_t)b * CAP + j];
            const float4* xr = (const float4*)(X + (long)idx * D);
            s = 0.f;
            for (int c = 0; c < 64; ++c) {
                float4 xv = xr[c];
                s = fmaf(qs[c * 4 + 0], xv.x, s);
                s = fmaf(qs[c * 4 + 1], xv.y, s);
                s = fmaf(qs[c * 4 + 2], xv.z, s);
                s = fmaf(qs[c * 4 + 3], xv.w, s);
            }
        } else { idx = 0x7FFFFFFF; s = -3.4e38f; }
        sc[j] = s; id[j] = idx;
    }
    __syncthreads();
    // bitonic: descending score, ascending idx on ties
    for (int k = 2; k <= CAP; k <<= 1)
        for (int j = k >> 1; j > 0; j >>= 1) {
            int i = t;
            int ixj = i ^ j;
            if (ixj > i) {
                float s1 = sc[i], s2 = sc[ixj];
                int i1 = id[i], i2 = id[ixj];
                bool before = (s1 > s2) || (s1 == s2 && i1 < i2);
                bool up = ((i & k) == 0);
                if (up != before) { sc[i] = s2; sc[ixj] = s1; id[i] = i2; id[ixj] = i1; }
            }
            __syncthreads();
        }
    if (t < TOPK) {
        int idx = id[t];
        out_idx[b * TOPK + t] = (float)idx;
        out_sc [b * TOPK + t] = sc[t];
        sel[b * TOPK + t] = idx;
    }
}

// ---------------- rerank: cross-attention contracted through head bottleneck (fp32) -----------
__global__ __launch_bounds__(256)
void rerank_kernel(const float* __restrict__ Q, const float* __restrict__ X,
                   const int* __restrict__ sel,
                   const float* __restrict__ Wq_eff, const float* __restrict__ Wk_eff,
                   const float* __restrict__ Wv_eff,
                   const float* __restrict__ qh_bias, const float* __restrict__ vh_bias,
                   const float* __restrict__ out_w, const float* __restrict__ out_b,
                   const float* __restrict__ W_s1, const float* __restrict__ b_s1,
                   const float* __restrict__ W_s2, const float* __restrict__ b_s2,
                   float* __restrict__ out_rr) {
    int b = blockIdx.x, t = threadIdx.x;
    __shared__ float qvec[D];
    __shared__ float qh[D];
    __shared__ float u[NH][D];
    __shared__ float att[NH][TOPK];
    __shared__ float wbar[NH][D];
    __shared__ float ctx[D];
    __shared__ float cross[D];
    __shared__ float h1[TOPK];
    __shared__ float red[256];

    qvec[t] = Q[(size_t)b * D + t];
    for (int i = t; i < NH * D; i += 256) (&wbar[0][0])[i] = 0.f;
    __syncthreads();

    {   // qh = query @ Wq_eff.T + qh_bias
        float acc = qh_bias[t];
        const float* wr = Wq_eff + (size_t)t * D;
        for (int d = 0; d < D; d += 4) {
            float4 wv = *(const float4*)(wr + d);
            acc += wv.x*qvec[d] + wv.y*qvec[d+1] + wv.z*qvec[d+2] + wv.w*qvec[d+3];
        }
        qh[t] = acc;
    }
    __syncthreads();
    {   // u[h][d] = sum_i qh[h*32+i] * Wk_eff[h*32+i][d], scaled by 1/sqrt(HD)
        const float scale = 0.17677669529663687f;
        for (int h = 0; h < NH; ++h) {
            float acc = 0.f;
            #pragma unroll 8
            for (int i = 0; i < HD; ++i)
                acc += qh[h * HD + i] * Wk_eff[(size_t)(h * HD + i) * D + t];
            u[h][t] = acc * scale;
        }
    }
    __syncthreads();
    {   // logits[h][k] = u[h] . cand_k
        int k = t & 127, hg = t >> 7;
        const float* xr = X + (long)sel[b * TOPK + k] * D;
        float acc[4] = {0.f, 0.f, 0.f, 0.f};
        for (int d = 0; d < D; d += 4) {
            float4 xv = *(const float4*)(xr + d);
            #pragma unroll
            for (int hh = 0; hh < 4; ++hh) {
                int h = hg + hh * 2;
                acc[hh] += u[h][d]*xv.x + u[h][d+1]*xv.y + u[h][d+2]*xv.z + u[h][d+3]*xv.w;
            }
        }
        #pragma unroll
        for (int hh = 0; hh < 4; ++hh) att[hg + hh * 2][k] = acc[hh];
    }
    __syncthreads();
    {   // softmax over k per head
        int w = t >> 6, lane = t & 63;
        for (int h = w; h < NH; h += 4) {
            float v0 = att[h][lane], v1 = att[h][lane + 64];
            float mx = fmaxf(v0, v1);
            for (int off = 32; off; off >>= 1) mx = fmaxf(mx, __shfl_down(mx, off));
            mx = __shfl(mx, 0);
            float e0 = expf(v0 - mx), e1 = expf(v1 - mx);
            float sm = e0 + e1;
            for (int off = 32; off; off >>= 1) sm += __shfl_down(sm, off);
            sm = __shfl(sm, 0);
            float inv = 1.f / sm;
            att[h][lane] = e0 * inv; att[h][lane + 64] = e1 * inv;
        }
    }
    __syncthreads();
    {   // wbar[h] = sum_k attn[h][k] * cand_k
        int w = t >> 6, lane = t & 63;
        float4 acc[NH];
        #pragma unroll
        for (int h = 0; h < NH; ++h) acc[h] = make_float4(0.f, 0.f, 0.f, 0.f);
        for (int kk = 0; kk < 32; ++kk) {
            int k = w * 32 + kk;
            const float* xr = X + (long)sel[b * TOPK + k] * D;
            float4 xv = ((const float4*)xr)[lane];
            #pragma unroll
            for (int h = 0; h < NH; ++h) {
                float a = att[h][k];
                acc[h].x += a * xv.x; acc[h].y += a * xv.y;
                acc[h].z += a * xv.z; acc[h].w += a * xv.w;
            }
        }
        #pragma unroll
        for (int h = 0; h < NH; ++h) {
            atomicAdd(&wbar[h][lane * 4 + 0], acc[h].x);
            atomicAdd(&wbar[h][lane * 4 + 1], acc[h].y);
            atomicAdd(&wbar[h][lane * 4 + 2], acc[h].z);
            atomicAdd(&wbar[h][lane * 4 + 3], acc[h].w);
        }
    }
    __syncthreads();
    {   // ctx[i] = Wv_eff[i] . wbar[i>>5] + vh_bias[i]
        int h = t >> 5;
        float acc = vh_bias[t];
        const float* wr = Wv_eff + (size_t)t * D;
        const float* wb = wbar[h];
        for (int d = 0; d < D; d += 4) {
            float4 wv = *(const float4*)(wr + d);
            acc += wv.x*wb[d] + wv.y*wb[d+1] + wv.z*wb[d+2] + wv.w*wb[d+3];
        }
        ctx[t] = acc;
    }
    __syncthreads();
    {   // cross_out
        float acc = out_b[t];
        const float* wr = out_w + (size_t)t * D;
        for (int d = 0; d < D; d += 4) {
            float4 wv = *(const float4*)(wr + d);
            acc += wv.x*ctx[d] + wv.y*ctx[d+1] + wv.z*ctx[d+2] + wv.w*ctx[d+3];
        }
        cross[t] = acc;
    }
    __syncthreads();
    if (t < TOPK) {   // h1 = relu(cross @ W_s1.T + b_s1)
        float acc = b_s1[t];
        const float* wr = W_s1 + (size_t)t * D;
        for (int d = 0; d < D; d += 4) {
            float4 wv = *(const float4*)(wr + d);
            acc += wv.x*cross[d] + wv.y*cross[d+1] + wv.z*cross[d+2] + wv.w*cross[d+3];
        }
        h1[t] = fmaxf(acc, 0.f);
    }
    __syncthreads();
    red[t] = (t < TOPK) ? h1[t] * W_s2[t] : 0.f;
    __syncthreads();
    for (int s = 128; s; s >>= 1) { if (t < s) red[t] += red[t + s]; __syncthreads(); }
    if (t == 0) out_rr[b] = red[0] + b_s2[0];
}

// ---------------- launch ----------------------------------------------------------------------
extern "C" void kernel_launch(void* const* d_in, const int* in_sizes, int n_in,
                              void* d_out, int out_size, void* d_ws, size_t ws_size,
                              hipStream_t stream) {
    const float* Q    = (const float*)d_in[0];
    const float* X    = (const float*)d_in[1];
    const float* W_cq = (const float*)d_in[2];
    const float* b_cq = (const float*)d_in[3];
    const float* W_cd = (const float*)d_in[4];
    const float* b_cd = (const float*)d_in[5];
    const float* in_w = (const float*)d_in[6];
    const float* in_b = (const float*)d_in[7];
    const float* ow   = (const float*)d_in[8];
    const float* ob   = (const float*)d_in[9];
    const float* Ws1  = (const float*)d_in[10];
    const float* bs1  = (const float*)d_in[11];
    const float* Ws2  = (const float*)d_in[12];
    const float* bs2  = (const float*)d_in[13];
    int B = in_sizes[0] / D;     // 512
    int N = in_sizes[1] / D;     // 200000

    char* ws = (char*)d_ws;
    unsigned short* Apack = (unsigned short*)ws;                      // B*D*2 (fragment-packed)
    float*          T     = (float*)(ws + (size_t)B * D * 2);         // B*4
    unsigned int*   cnt   = (unsigned int*)(ws + (size_t)B * D * 2 + B * 4);
    int*            cand  = (int*)(ws + (size_t)B * D * 2 + B * 8);   // B*CAP*4
    int*            sel   = (int*)((char*)cand + (size_t)B * CAP * 4);// B*TOPK*4
    float*          Wq_eff = (float*)((char*)sel + (size_t)B * TOPK * 4);
    float*          Wk_eff = Wq_eff + D * D;
    float*          Wv_eff = Wk_eff + D * D;
    float*          qh_b   = Wv_eff + D * D;
    float*          vh_b   = qh_b + D;

    float* ofl     = (float*)d_out;                 // fp32 output buffer
    float* out_idx = ofl;                           // [B*TOPK] indices as floats
    float* out_sc  = ofl + (size_t)B * TOPK;        // [B*TOPK] scores
    float* out_rr  = ofl + (size_t)2 * B * TOPK;    // [B] rerank scores

    prep_kernel<<<B, 64, 0, stream>>>(Q, Apack, T, cnt);
    weights_kernel<<<3 * D, 256, 0, stream>>>(in_w, in_b, W_cq, b_cq, W_cd, b_cd,
                                              Wq_eff, Wk_eff, Wv_eff, qh_b, vh_b);
    int nblk = (N + BN - 1) / BN;
    coarse_kernel<<<nblk, 256, 0, stream>>>(X, Apack, T, cnt, cand, N, B);
    fine_kernel<<<B, 512, 0, stream>>>(Q, X, cnt, cand, sel, out_idx, out_sc);
    rerank_kernel<<<B, 256, 0, stream>>>(Q, X, sel, Wq_eff, Wk_eff, Wv_eff, qh_b, vh_b,
                                         ow, ob, Ws1, bs1, Ws2, bs2, out_rr);
}

// Round 3
// 521.982 us; speedup vs baseline: 1.4645x; 1.1814x over previous
//
#include <hip/hip_runtime.h>
#include <hip/hip_bf16.h>

#define D      256
#define NH     8
#define HD     32
#define TOPK   128
#define CAP    512
#define BN     32
#define ZTHRESH 3.0f

typedef __bf16 bf16x8 __attribute__((ext_vector_type(8)));
typedef float  f32x4  __attribute__((ext_vector_type(4)));

static __device__ __forceinline__ unsigned short bf16_trunc(float f) {
    return (unsigned short)(__builtin_bit_cast(unsigned int, f) >> 16);
}

// ---------------- prep: query fp32 -> bf16 (trunc) packed in MFMA A-fragment order ------------
// Apack[((mt*8 + ks)*64 + lane)*8 + j] = A[mt*16 + (lane&15)][ks*32 + (lane>>4)*8 + j]
__global__ void prep_kernel(const float* __restrict__ Q, unsigned short* __restrict__ Apack,
                            float* __restrict__ T, unsigned int* __restrict__ cnt) {
    int b = blockIdx.x;
    int lane = threadIdx.x;            // 0..63, handles cols 4*lane..4*lane+3
    float4 v = ((const float4*)(Q + b * D))[lane];
    ushort4 h;
    h.x = bf16_trunc(v.x); h.y = bf16_trunc(v.y); h.z = bf16_trunc(v.z); h.w = bf16_trunc(v.w);
    int mt = b >> 4, r = b & 15;
    int ks = lane >> 3;                // k-block of 32
    int q  = (lane >> 1) & 3;          // quad within fragment (k bits 3..4)
    int j4 = (lane & 1) * 4;           // half within the 8-element fragment
    size_t off = (((size_t)(mt * 8 + ks)) * 64 + (q * 16 + r)) * 8 + j4;
    *(ushort4*)(Apack + off) = h;
    float ss = v.x*v.x + v.y*v.y + v.z*v.z + v.w*v.w;
    for (int off2 = 32; off2; off2 >>= 1) ss += __shfl_down(ss, off2);
    if (lane == 0) { T[b] = ZTHRESH * sqrtf(ss); cnt[b] = 0u; }
}

// ---------------- fused weights: Wq_eff = Wq@W_cq, Wk_eff = Wk@W_cd, Wv_eff = Wv@W_cd + biases -
__global__ void weights_kernel(const float* __restrict__ in_w, const float* __restrict__ in_b,
                               const float* __restrict__ W_cq, const float* __restrict__ b_cq,
                               const float* __restrict__ W_cd, const float* __restrict__ b_cd,
                               float* __restrict__ Wq_eff, float* __restrict__ Wk_eff,
                               float* __restrict__ Wv_eff,
                               float* __restrict__ qh_bias, float* __restrict__ vh_bias) {
    int which = blockIdx.x >> 8;       // 0=q 1=k 2=v
    int i = blockIdx.x & 255;          // output row
    int t = threadIdx.x;               // output col
    __shared__ float wrow[D];
    __shared__ float red[256];
    const float* Wsub = in_w + (size_t)which * D * D + (size_t)i * D;
    wrow[t] = Wsub[t];
    __syncthreads();
    const float* Wc = (which == 0) ? W_cq : W_cd;
    // 4 independent accumulators: breaks the serial FMA chain (rerank tolerance is 2%)
    float a0 = 0.f, a1 = 0.f, a2 = 0.f, a3 = 0.f;
    for (int d = 0; d < D; d += 4) {
        a0 += wrow[d + 0] * Wc[(d + 0) * D + t];
        a1 += wrow[d + 1] * Wc[(d + 1) * D + t];
        a2 += wrow[d + 2] * Wc[(d + 2) * D + t];
        a3 += wrow[d + 3] * Wc[(d + 3) * D + t];
    }
    float acc = (a0 + a1) + (a2 + a3);
    float* dst = (which == 0) ? Wq_eff : ((which == 1) ? Wk_eff : Wv_eff);
    dst[(size_t)i * D + t] = acc;
    const float* bc = (which == 0) ? b_cq : b_cd;
    red[t] = wrow[t] * bc[t];
    __syncthreads();
    for (int s = 128; s; s >>= 1) { if (t < s) red[t] += red[t + s]; __syncthreads(); }
    if (t == 0) {
        float bias = red[0] + in_b[which * D + i];
        if (which == 0) qh_bias[i] = bias;
        else if (which == 2) vh_bias[i] = bias;   // k-bias is softmax-invariant, dropped
    }
}

// ---------------- coarse: A-resident-in-registers persistent MFMA + threshold filter ----------
// 1024 threads = 16 waves; wave w holds queries [w*32, w*32+32) as MFMA A-fragments in 64 VGPRs,
// loaded ONCE. Grid = 256 persistent blocks striding over BN=32 candidate tiles. Inner loop has
// ZERO global loads (ds_read + MFMA only), so the T14 early-issued stage loads for tile t+1 stay
// in flight under compute with no vmcnt-FIFO interference. One barrier/tile, 2x16KB LDS dbuf.
__global__ __launch_bounds__(1024, 4)
void coarse_kernel(const float* __restrict__ X, const unsigned short* __restrict__ Apack,
                   const float* __restrict__ T, unsigned int* __restrict__ cnt,
                   int* __restrict__ cand, int N, int ntiles) {
    __shared__ unsigned short Bs0[BN * D];   // 16 KiB, 16B-granule XOR swizzle
    __shared__ unsigned short Bs1[BN * D];   // 16 KiB (double buffer)
    __shared__ float Ts[512];                // thresholds staged once per block
    int t = threadIdx.x;
    int w = t >> 6, lane = t & 63;
    int l15 = lane & 15, q4 = lane >> 4;

    if (t < 512) Ts[t] = T[t];

    // ---- A panel resident: af[mtl][ks], fully-unrolled constant indexing (stays in VGPRs) ----
    bf16x8 af[2][8];
    #pragma unroll
    for (int mtl = 0; mtl < 2; ++mtl)
        #pragma unroll
        for (int ks = 0; ks < 8; ++ks) {
            int mtg = w * 2 + mtl;
            af[mtl][ks] = *(const bf16x8*)(const void*)(Apack + (((size_t)(mtg * 8 + ks)) * 64 + lane) * 8);
        }

    const float4* X4 = (const float4*)X;
    // thread's two stage elements: rows r0 and r0+16, float4-column c4 (same for both)
    int r0 = t >> 6;          // 0..15
    int c4 = t & 63;

#define PACKW(buf, row, vv) { uint2 pk; \
        pk.x = (__builtin_bit_cast(unsigned int, vv.x) >> 16) | \
               (__builtin_bit_cast(unsigned int, vv.y) & 0xFFFF0000u); \
        pk.y = (__builtin_bit_cast(unsigned int, vv.z) >> 16) | \
               (__builtin_bit_cast(unsigned int, vv.w) & 0xFFFF0000u); \
        int gran = (c4 >> 1) ^ ((row) & 7); \
        ((uint2*)(buf))[(row) * 64 + gran * 2 + (c4 & 1)] = pk; }

    long tile = blockIdx.x;
    if (tile >= ntiles) return;          // block-uniform exit (grid <= ntiles in practice)

    float4 v0, v1;
    {   // prologue: stage tile 0 into Bs0
        long nb = tile * BN;
        long g0 = nb + r0;       if (g0 >= N) g0 = N - 1;
        long g1 = nb + r0 + 16;  if (g1 >= N) g1 = N - 1;
        v0 = X4[g0 * 64 + c4];
        v1 = X4[g1 * 64 + c4];
        PACKW(Bs0, r0, v0)
        PACKW(Bs0, r0 + 16, v1)
    }
    __syncthreads();

    const unsigned short* rd = Bs0;
    unsigned short*       wr = Bs1;

    for (;;) {
        long next = tile + gridDim.x;
        bool have = next < (long)ntiles;
        if (have) {                      // T14: issue next tile's loads before compute
            long nb = next * BN;
            long g0 = nb + r0;       if (g0 >= N) g0 = N - 1;
            long g1 = nb + r0 + 16;  if (g1 >= N) g1 = N - 1;
            v0 = X4[g0 * 64 + c4];
            v1 = X4[g1 * 64 + c4];
        }

        // ---- compute: ds_read + MFMA only ----
        f32x4 acc[2][2];
        #pragma unroll
        for (int mtl = 0; mtl < 2; ++mtl)
            #pragma unroll
            for (int nt = 0; nt < 2; ++nt) acc[mtl][nt] = (f32x4){0.f, 0.f, 0.f, 0.f};

        #pragma unroll
        for (int ks = 0; ks < 8; ++ks) {
            bf16x8 bf[2];
            #pragma unroll
            for (int nt = 0; nt < 2; ++nt) {
                int n = nt * 16 + l15;
                int gran = (ks * 4 + q4) ^ (n & 7);
                bf[nt] = *(const bf16x8*)(const void*)(rd + n * D + gran * 8);
            }
            #pragma unroll
            for (int mtl = 0; mtl < 2; ++mtl)
                #pragma unroll
                for (int nt = 0; nt < 2; ++nt)
                    acc[mtl][nt] = __builtin_amdgcn_mfma_f32_16x16x32_bf16(
                        af[mtl][ks], bf[nt], acc[mtl][nt], 0, 0, 0);
        }

        // ---- write next tile into the other buffer (waits the early loads; FIFO is clean) ----
        if (have) {
            PACKW(wr, r0, v0)
            PACKW(wr, r0 + 16, v1)
        }

        // ---- filter epilogue: D[row=m][col=n], row=(lane>>4)*4+r, col=lane&15 ----
        {
            long nbase = tile * BN;
            #pragma unroll
            for (int mtl = 0; mtl < 2; ++mtl) {
                int mbase = w * 32 + mtl * 16 + q4 * 4;
                float4 Tv = *(const float4*)(Ts + mbase);
                float Ta[4] = {Tv.x, Tv.y, Tv.z, Tv.w};
                #pragma unroll
                for (int nt = 0; nt < 2; ++nt) {
                    long n_global = nbase + nt * 16 + l15;
                    #pragma unroll
                    for (int r = 0; r < 4; ++r) {
                        float s = acc[mtl][nt][r];
                        if (n_global < N && s >= Ta[r]) {
                            int m = mbase + r;
                            unsigned int pos = atomicAdd(&cnt[m], 1u);
                            if (pos < CAP) cand[(size_t)m * CAP + pos] = (int)n_global;
                        }
                    }
                }
            }
        }

        __syncthreads();                 // everyone done reading rd / writing wr
        if (!have) break;
        tile = next;
        const unsigned short* tmp = rd; rd = wr; wr = (unsigned short*)tmp;
    }
#undef PACKW
}

// ---------------- fine: fp32 sequential-FMA re-score (sgemm-bit-exact) + bitonic top-128 ------
__global__ __launch_bounds__(512)
void fine_kernel(const float* __restrict__ Q, const float* __restrict__ X,
                 const unsigned int* __restrict__ cnt, const int* __restrict__ cand,
                 int* __restrict__ sel, float* __restrict__ out_idx,
                 float* __restrict__ out_sc) {
    int b = blockIdx.x, t = threadIdx.x;    // 512 threads: one candidate per thread
    __shared__ float qs[D];
    __shared__ float sc[CAP];
    __shared__ int   id[CAP];
    if (t < D) qs[t] = Q[(size_t)b * D + t];
    __syncthreads();
    int m = (int)cnt[b]; if (m > CAP) m = CAP;

    // strict sequential fp32 FMA, ascending k — bit-exact vs numpy's sgemm microkernel
    {
        int j = t;
        float s; int idx;
        if (j < m) {
            idx = cand[(size_t)b * CAP + j];
            const float4* xr = (const float4*)(X + (long)idx * D);
            s = 0.f;
            for (int c = 0; c < 64; ++c) {
                float4 xv = xr[c];
                s = fmaf(qs[c * 4 + 0], xv.x, s);
                s = fmaf(qs[c * 4 + 1], xv.y, s);
                s = fmaf(qs[c * 4 + 2], xv.z, s);
                s = fmaf(qs[c * 4 + 3], xv.w, s);
            }
        } else { idx = 0x7FFFFFFF; s = -3.4e38f; }
        sc[j] = s; id[j] = idx;
    }
    __syncthreads();
    // bitonic: descending score, ascending idx on ties
    for (int k = 2; k <= CAP; k <<= 1)
        for (int j = k >> 1; j > 0; j >>= 1) {
            int i = t;
            int ixj = i ^ j;
            if (ixj > i) {
                float s1 = sc[i], s2 = sc[ixj];
                int i1 = id[i], i2 = id[ixj];
                bool before = (s1 > s2) || (s1 == s2 && i1 < i2);
                bool up = ((i & k) == 0);
                if (up != before) { sc[i] = s2; sc[ixj] = s1; id[i] = i2; id[ixj] = i1; }
            }
            __syncthreads();
        }
    if (t < TOPK) {
        int idx = id[t];
        out_idx[b * TOPK + t] = (float)idx;
        out_sc [b * TOPK + t] = sc[t];
        sel[b * TOPK + t] = idx;
    }
}

// ---------------- rerank: cross-attention contracted through head bottleneck (fp32) -----------
__global__ __launch_bounds__(256)
void rerank_kernel(const float* __restrict__ Q, const float* __restrict__ X,
                   const int* __restrict__ sel,
                   const float* __restrict__ Wq_eff, const float* __restrict__ Wk_eff,
                   const float* __restrict__ Wv_eff,
                   const float* __restrict__ qh_bias, const float* __restrict__ vh_bias,
                   const float* __restrict__ out_w, const float* __restrict__ out_b,
                   const float* __restrict__ W_s1, const float* __restrict__ b_s1,
                   const float* __restrict__ W_s2, const float* __restrict__ b_s2,
                   float* __restrict__ out_rr) {
    int b = blockIdx.x, t = threadIdx.x;
    __shared__ float qvec[D];
    __shared__ float qh[D];
    __shared__ float u[NH][D];
    __shared__ float att[NH][TOPK];
    __shared__ float wbar[NH][D];
    __shared__ float ctx[D];
    __shared__ float cross[D];
    __shared__ float h1[TOPK];
    __shared__ float red[256];

    qvec[t] = Q[(size_t)b * D + t];
    for (int i = t; i < NH * D; i += 256) (&wbar[0][0])[i] = 0.f;
    __syncthreads();

    {   // qh = query @ Wq_eff.T + qh_bias
        float acc = qh_bias[t];
        const float* wr = Wq_eff + (size_t)t * D;
        for (int d = 0; d < D; d += 4) {
            float4 wv = *(const float4*)(wr + d);
            acc += wv.x*qvec[d] + wv.y*qvec[d+1] + wv.z*qvec[d+2] + wv.w*qvec[d+3];
        }
        qh[t] = acc;
    }
    __syncthreads();
    {   // u[h][d] = sum_i qh[h*32+i] * Wk_eff[h*32+i][d], scaled by 1/sqrt(HD)
        const float scale = 0.17677669529663687f;
        for (int h = 0; h < NH; ++h) {
            float acc = 0.f;
            #pragma unroll 8
            for (int i = 0; i < HD; ++i)
                acc += qh[h * HD + i] * Wk_eff[(size_t)(h * HD + i) * D + t];
            u[h][t] = acc * scale;
        }
    }
    __syncthreads();
    {   // logits[h][k] = u[h] . cand_k
        int k = t & 127, hg = t >> 7;
        const float* xr = X + (long)sel[b * TOPK + k] * D;
        float acc[4] = {0.f, 0.f, 0.f, 0.f};
        for (int d = 0; d < D; d += 4) {
            float4 xv = *(const float4*)(xr + d);
            #pragma unroll
            for (int hh = 0; hh < 4; ++hh) {
                int h = hg + hh * 2;
                acc[hh] += u[h][d]*xv.x + u[h][d+1]*xv.y + u[h][d+2]*xv.z + u[h][d+3]*xv.w;
            }
        }
        #pragma unroll
        for (int hh = 0; hh < 4; ++hh) att[hg + hh * 2][k] = acc[hh];
    }
    __syncthreads();
    {   // softmax over k per head
        int w = t >> 6, lane = t & 63;
        for (int h = w; h < NH; h += 4) {
            float v0 = att[h][lane], v1 = att[h][lane + 64];
            float mx = fmaxf(v0, v1);
            for (int off = 32; off; off >>= 1) mx = fmaxf(mx, __shfl_down(mx, off));
            mx = __shfl(mx, 0);
            float e0 = expf(v0 - mx), e1 = expf(v1 - mx);
            float sm = e0 + e1;
            for (int off = 32; off; off >>= 1) sm += __shfl_down(sm, off);
            sm = __shfl(sm, 0);
            float inv = 1.f / sm;
            att[h][lane] = e0 * inv; att[h][lane + 64] = e1 * inv;
        }
    }
    __syncthreads();
    {   // wbar[h] = sum_k attn[h][k] * cand_k
        int w = t >> 6, lane = t & 63;
        float4 acc[NH];
        #pragma unroll
        for (int h = 0; h < NH; ++h) acc[h] = make_float4(0.f, 0.f, 0.f, 0.f);
        for (int kk = 0; kk < 32; ++kk) {
            int k = w * 32 + kk;
            const float* xr = X + (long)sel[b * TOPK + k] * D;
            float4 xv = ((const float4*)xr)[lane];
            #pragma unroll
            for (int h = 0; h < NH; ++h) {
                float a = att[h][k];
                acc[h].x += a * xv.x; acc[h].y += a * xv.y;
                acc[h].z += a * xv.z; acc[h].w += a * xv.w;
            }
        }
        #pragma unroll
        for (int h = 0; h < NH; ++h) {
            atomicAdd(&wbar[h][lane * 4 + 0], acc[h].x);
            atomicAdd(&wbar[h][lane * 4 + 1], acc[h].y);
            atomicAdd(&wbar[h][lane * 4 + 2], acc[h].z);
            atomicAdd(&wbar[h][lane * 4 + 3], acc[h].w);
        }
    }
    __syncthreads();
    {   // ctx[i] = Wv_eff[i] . wbar[i>>5] + vh_bias[i]
        int h = t >> 5;
        float acc = vh_bias[t];
        const float* wr = Wv_eff + (size_t)t * D;
        const float* wb = wbar[h];
        for (int d = 0; d < D; d += 4) {
            float4 wv = *(const float4*)(wr + d);
            acc += wv.x*wb[d] + wv.y*wb[d+1] + wv.z*wb[d+2] + wv.w*wb[d+3];
        }
        ctx[t] = acc;
    }
    __syncthreads();
    {   // cross_out
        float acc = out_b[t];
        const float* wr = out_w + (size_t)t * D;
        for (int d = 0; d < D; d += 4) {
            float4 wv = *(const float4*)(wr + d);
            acc += wv.x*ctx[d] + wv.y*ctx[d+1] + wv.z*ctx[d+2] + wv.w*ctx[d+3];
        }
        cross[t] = acc;
    }
    __syncthreads();
    if (t < TOPK) {   // h1 = relu(cross @ W_s1.T + b_s1)
        float acc = b_s1[t];
        const float* wr = W_s1 + (size_t)t * D;
        for (int d = 0; d < D; d += 4) {
            float4 wv = *(const float4*)(wr + d);
            acc += wv.x*cross[d] + wv.y*cross[d+1] + wv.z*cross[d+2] + wv.w*cross[d+3];
        }
        h1[t] = fmaxf(acc, 0.f);
    }
    __syncthreads();
    red[t] = (t < TOPK) ? h1[t] * W_s2[t] : 0.f;
    __syncthreads();
    for (int s = 128; s; s >>= 1) { if (t < s) red[t] += red[t + s]; __syncthreads(); }
    if (t == 0) out_rr[b] = red[0] + b_s2[0];
}

// ---------------- launch ----------------------------------------------------------------------
extern "C" void kernel_launch(void* const* d_in, const int* in_sizes, int n_in,
                              void* d_out, int out_size, void* d_ws, size_t ws_size,
                              hipStream_t stream) {
    const float* Q    = (const float*)d_in[0];
    const float* X    = (const float*)d_in[1];
    const float* W_cq = (const float*)d_in[2];
    const float* b_cq = (const float*)d_in[3];
    const float* W_cd = (const float*)d_in[4];
    const float* b_cd = (const float*)d_in[5];
    const float* in_w = (const float*)d_in[6];
    const float* in_b = (const float*)d_in[7];
    const float* ow   = (const float*)d_in[8];
    const float* ob   = (const float*)d_in[9];
    const float* Ws1  = (const float*)d_in[10];
    const float* bs1  = (const float*)d_in[11];
    const float* Ws2  = (const float*)d_in[12];
    const float* bs2  = (const float*)d_in[13];
    int B = in_sizes[0] / D;     // 512
    int N = in_sizes[1] / D;     // 200000

    char* ws = (char*)d_ws;
    unsigned short* Apack = (unsigned short*)ws;                      // B*D*2 (fragment-packed)
    float*          T     = (float*)(ws + (size_t)B * D * 2);         // B*4
    unsigned int*   cnt   = (unsigned int*)(ws + (size_t)B * D * 2 + B * 4);
    int*            cand  = (int*)(ws + (size_t)B * D * 2 + B * 8);   // B*CAP*4
    int*            sel   = (int*)((char*)cand + (size_t)B * CAP * 4);// B*TOPK*4
    float*          Wq_eff = (float*)((char*)sel + (size_t)B * TOPK * 4);
    float*          Wk_eff = Wq_eff + D * D;
    float*          Wv_eff = Wk_eff + D * D;
    float*          qh_b   = Wv_eff + D * D;
    float*          vh_b   = qh_b + D;

    float* ofl     = (float*)d_out;                 // fp32 output buffer
    float* out_idx = ofl;                           // [B*TOPK] indices as floats
    float* out_sc  = ofl + (size_t)B * TOPK;        // [B*TOPK] scores
    float* out_rr  = ofl + (size_t)2 * B * TOPK;    // [B] rerank scores

    prep_kernel<<<B, 64, 0, stream>>>(Q, Apack, T, cnt);
    weights_kernel<<<3 * D, 256, 0, stream>>>(in_w, in_b, W_cq, b_cq, W_cd, b_cd,
                                              Wq_eff, Wk_eff, Wv_eff, qh_b, vh_b);
    int ntiles = (N + BN - 1) / BN;      // 6250
    coarse_kernel<<<256, 1024, 0, stream>>>(X, Apack, T, cnt, cand, N, ntiles);
    fine_kernel<<<B, 512, 0, stream>>>(Q, X, cnt, cand, sel, out_idx, out_sc);
    rerank_kernel<<<B, 256, 0, stream>>>(Q, X, sel, Wq_eff, Wk_eff, Wv_eff, qh_b, vh_b,
                                         ow, ob, Ws1, bs1, Ws2, bs2, out_rr);
}